// Round 3
// baseline (1486.123 us; speedup 1.0000x reference)
//
#include <hip/hip_runtime.h>

#define N_ATOMS 16384
#define N_EDGES 262144
#define NRBF 20

// ---------------- workspace layout (units of 4 bytes) ----------------
// floats
static const size_t OFF_DIR  = 0;                               // [3][E]
static const size_t OFF_PHI  = OFF_DIR  + (size_t)3*N_EDGES;    // [20][E]
static const size_t OFF_FCUT = OFF_PHI  + (size_t)NRBF*N_EDGES; // [E]
static const size_t OFF_Q    = OFF_FCUT + (size_t)N_EDGES;      // [N][128]
static const size_t OFF_H    = OFF_Q    + (size_t)N_ATOMS*128;  // [N][384] (also g)
static const size_t OFF_MU0  = OFF_H    + (size_t)N_ATOMS*384;  // [N][3][128]
static const size_t OFF_MU1  = OFF_MU0  + (size_t)N_ATOMS*384;
static const size_t OFF_T    = OFF_MU1  + (size_t)N_ATOMS*384;  // [N][128] (t and t2)
static const size_t OFF_CTX  = OFF_T    + (size_t)N_ATOMS*128;  // [N][256]
static const size_t OFF_MM   = OFF_CTX  + (size_t)N_ATOMS*256;  // [N][3][256]
// ints
static const size_t OFF_INT  = OFF_MM   + (size_t)N_ATOMS*768;
// counts[N], cursor[N], row_ptr[N+1 (pad to N+64)], edge_ord[E]
static const size_t WS_NEEDED_BYTES =
    (OFF_INT + (size_t)3*N_ATOMS + 64 + (size_t)N_EDGES) * 4;

// ---------------- geometry: dir, RBF phi (transposed), fcut ----------------
__global__ __launch_bounds__(256) void geom_kernel(
    const float* __restrict__ pos, const int* __restrict__ idx_i,
    const int* __restrict__ idx_j, float* __restrict__ dirv,
    float* __restrict__ phi, float* __restrict__ fcutv) {
  int e = blockIdx.x * 256 + threadIdx.x;
  int i = idx_i[e], j = idx_j[e];
  float xi = pos[3*i], yi = pos[3*i+1], zi = pos[3*i+2];
  float xj = pos[3*j], yj = pos[3*j+1], zj = pos[3*j+2];
  float dx = xj - xi, dy = yj - yi, dz = zj - zi;
  float d = sqrtf(dx*dx + dy*dy + dz*dz);
  float inv = 1.0f / d;
  dirv[e] = dx*inv; dirv[N_EDGES+e] = dy*inv; dirv[2*N_EDGES+e] = dz*inv;
  const float w = 5.0f / 19.0f;          // linspace(0,5,20) spacing
  const float coef = -0.5f / (w*w);
  #pragma unroll
  for (int k = 0; k < NRBF; ++k) {
    float t = d - w * (float)k;
    phi[(size_t)k*N_EDGES + e] = expf(coef * t * t);
  }
  fcutv[e] = (d < 5.0f) ? 0.5f * (cosf(d * 0.62831853071795864769f) + 1.0f) : 0.0f;
}

// ---------------- CSR build ----------------
__global__ __launch_bounds__(256) void hist_kernel(const int* __restrict__ idx_i,
                                                   int* __restrict__ counts) {
  int e = blockIdx.x * 256 + threadIdx.x;
  atomicAdd(&counts[idx_i[e]], 1);
}

__global__ __launch_bounds__(256) void scan_kernel(const int* __restrict__ counts,
                                                   int* __restrict__ row_ptr) {
  __shared__ int part[256];
  int t = threadIdx.x;
  int base = t * 64;
  int s = 0;
  for (int k = 0; k < 64; ++k) s += counts[base + k];
  part[t] = s;
  __syncthreads();
  for (int off = 1; off < 256; off <<= 1) {
    int v = (t >= off) ? part[t - off] : 0;
    __syncthreads();
    part[t] += v;
    __syncthreads();
  }
  int run = (t > 0) ? part[t - 1] : 0;
  for (int k = 0; k < 64; ++k) { row_ptr[base + k] = run; run += counts[base + k]; }
  if (t == 255) row_ptr[N_ATOMS] = run;
}

__global__ __launch_bounds__(256) void scatter_kernel(
    const int* __restrict__ idx_i, const int* __restrict__ row_ptr,
    int* __restrict__ cursor, int* __restrict__ edge_ord) {
  int e = blockIdx.x * 256 + threadIdx.x;
  int i = idx_i[e];
  int p = atomicAdd(&cursor[i], 1);
  edge_ord[row_ptr[i] + p] = e;
}

// ---------------- init: q = emb[x], mu = 0 ----------------
__global__ __launch_bounds__(256) void init_kernel(
    const int* __restrict__ x, const float* __restrict__ emb,
    float* __restrict__ q, float* __restrict__ mu0) {
  int idx = blockIdx.x * 256 + threadIdx.x;   // over N*128
  int a = idx >> 7, f = idx & 127;
  q[idx] = emb[(size_t)x[a]*128 + f];
  size_t mb = (size_t)a * 384;
  mu0[mb + f] = 0.0f; mu0[mb + 128 + f] = 0.0f; mu0[mb + 256 + f] = 0.0f;
}

// ---------------- tiled f32 GEMM: C[M,N] = act(A[M,K] @ B[N,K]^T + bias) ----------------
// BM=128, BN=64, BK=32; 256 threads; 8x4 per-thread tile; A/B staged transposed in LDS.
template <int SILU>
__global__ __launch_bounds__(256) void gemm_tn(
    const float* __restrict__ A, const float* __restrict__ B,
    const float* __restrict__ bias, float* __restrict__ C,
    int M, int N, int K) {
  __shared__ float As[32][132];
  __shared__ float Bs[32][68];
  const int tid = threadIdx.x;
  const int m0 = blockIdx.x * 128;
  const int n0 = blockIdx.y * 64;
  const int tx = tid & 15;        // N dir (16*4 = 64)
  const int ty = tid >> 4;        // M dir (16*8 = 128)
  const int lrow = tid >> 3;      // 0..31
  const int lk4  = (tid & 7) * 4; // 0..28
  float acc[8][4] = {};
  for (int k0 = 0; k0 < K; k0 += 32) {
    __syncthreads();
    #pragma unroll
    for (int r = 0; r < 4; ++r) {
      int row = lrow + 32 * r;
      float4 v = *(const float4*)&A[(size_t)(m0 + row) * K + k0 + lk4];
      As[lk4+0][row] = v.x; As[lk4+1][row] = v.y;
      As[lk4+2][row] = v.z; As[lk4+3][row] = v.w;
    }
    #pragma unroll
    for (int r = 0; r < 2; ++r) {
      int row = lrow + 32 * r;
      float4 v = *(const float4*)&B[(size_t)(n0 + row) * K + k0 + lk4];
      Bs[lk4+0][row] = v.x; Bs[lk4+1][row] = v.y;
      Bs[lk4+2][row] = v.z; Bs[lk4+3][row] = v.w;
    }
    __syncthreads();
    #pragma unroll
    for (int kk = 0; kk < 32; ++kk) {
      float4 a0 = *(const float4*)&As[kk][ty*8];
      float4 a1 = *(const float4*)&As[kk][ty*8+4];
      float4 b0 = *(const float4*)&Bs[kk][tx*4];
      float av[8] = {a0.x,a0.y,a0.z,a0.w,a1.x,a1.y,a1.z,a1.w};
      float bv[4] = {b0.x,b0.y,b0.z,b0.w};
      #pragma unroll
      for (int i = 0; i < 8; ++i)
        #pragma unroll
        for (int j = 0; j < 4; ++j)
          acc[i][j] = fmaf(av[i], bv[j], acc[i][j]);
    }
  }
  #pragma unroll
  for (int i = 0; i < 8; ++i) {
    int m = m0 + ty*8 + i;
    float4 o;
    float* po = &o.x;
    #pragma unroll
    for (int j = 0; j < 4; ++j) {
      int n = n0 + tx*4 + j;
      float c = acc[i][j] + (bias ? bias[n] : 0.0f);
      if (SILU) c = c / (1.0f + expf(-c));
      po[j] = c;
    }
    *(float4*)&C[(size_t)m * N + n0 + tx*4] = o;
  }
}

// ---------------- edge interaction: gather-reduce per atom (1 wave / atom) ----------------
__global__ __launch_bounds__(256) void edge_kernel(
    const float* __restrict__ phi, const float* __restrict__ fcutv,
    const float* __restrict__ dirv, const float* __restrict__ filtW,
    const float* __restrict__ filtb, const float* __restrict__ h,
    const float* __restrict__ mu_c, const int* __restrict__ idx_j,
    const int* __restrict__ row_ptr, const int* __restrict__ edge_ord,
    float* __restrict__ q, float* __restrict__ mu_n) {
  const int lane = threadIdx.x & 63;
  const int a = blockIdx.x * 4 + (threadIdx.x >> 6);
  const int rs = row_ptr[a], re = row_ptr[a + 1];
  const size_t qb = (size_t)a * 128;
  const size_t mb = (size_t)a * 384;
  if (rs == re) {  // no incoming edges: mu passthrough, q unchanged
    #pragma unroll
    for (int d2 = 0; d2 < 3; ++d2) {
      mu_n[mb + d2*128 + lane]      = mu_c[mb + d2*128 + lane];
      mu_n[mb + d2*128 + 64 + lane] = mu_c[mb + d2*128 + 64 + lane];
    }
    return;
  }
  // Per-lane filter rows are edge-invariant: keep 6x20 weights in VGPRs.
  float fw[6][20];
  float fb[6];
  #pragma unroll
  for (int s = 0; s < 6; ++s) {
    int c = (s >> 1) * 128 + (s & 1) * 64 + lane;  // channel m*128 + p*64 + lane
    fb[s] = filtb[c];
    #pragma unroll
    for (int k = 0; k < 20; ++k) fw[s][k] = filtW[c * 20 + k];
  }
  float accq[2] = {};
  float am[3][2] = {};
  for (int t = rs; t < re; ++t) {
    const int e = edge_ord[t];
    const int j = idx_j[e];
    const float fc = fcutv[e];
    const float dx = dirv[e], dy = dirv[N_EDGES + e], dz = dirv[2*N_EDGES + e];
    float ph[20];
    #pragma unroll
    for (int k = 0; k < 20; ++k) ph[k] = phi[(size_t)k * N_EDGES + e];
    float w[6];
    #pragma unroll
    for (int s = 0; s < 6; ++s) {
      float acc = fb[s];
      #pragma unroll
      for (int k = 0; k < 20; ++k) acc = fmaf(ph[k], fw[s][k], acc);
      w[s] = acc * fc;
    }
    const float* hj = h + (size_t)j * 384;
    const float* mj = mu_c + (size_t)j * 384;
    #pragma unroll
    for (int p = 0; p < 2; ++p) {
      const int f = p * 64 + lane;
      accq[p] = fmaf(w[p], hj[f], accq[p]);
      float xr = w[2 + p] * hj[128 + f];
      float xm = w[4 + p] * hj[256 + f];
      am[0][p] = fmaf(xr, dx, fmaf(xm, mj[f],       am[0][p]));
      am[1][p] = fmaf(xr, dy, fmaf(xm, mj[128 + f], am[1][p]));
      am[2][p] = fmaf(xr, dz, fmaf(xm, mj[256 + f], am[2][p]));
    }
  }
  q[qb + lane]      += accq[0];
  q[qb + 64 + lane] += accq[1];
  #pragma unroll
  for (int d2 = 0; d2 < 3; ++d2) {
    mu_n[mb + d2*128 + lane]      = mu_c[mb + d2*128 + lane]      + am[d2][0];
    mu_n[mb + d2*128 + 64 + lane] = mu_c[mb + d2*128 + 64 + lane] + am[d2][1];
  }
}

// ---------------- mixing helpers ----------------
__global__ __launch_bounds__(256) void ctx_kernel(
    const float* __restrict__ q, const float* __restrict__ mm,
    float* __restrict__ ctx) {
  int idx = blockIdx.x * 256 + threadIdx.x;  // over N*128
  int a = idx >> 7, f = idx & 127;
  size_t b = (size_t)a * 768;
  float v0 = mm[b + f], v1 = mm[b + 256 + f], v2 = mm[b + 512 + f];
  float vn = sqrtf(fmaf(v0, v0, fmaf(v1, v1, v2 * v2)) + 1e-8f);
  ctx[(size_t)a * 256 + f] = q[idx];
  ctx[(size_t)a * 256 + 128 + f] = vn;
}

__global__ __launch_bounds__(256) void mixup_kernel(
    const float* __restrict__ g, const float* __restrict__ mm,
    float* __restrict__ q, float* __restrict__ mu) {
  int idx = blockIdx.x * 256 + threadIdx.x;  // over N*128
  int a = idx >> 7, f = idx & 127;
  size_t b = (size_t)a * 768;
  float v0 = mm[b + f],       v1 = mm[b + 256 + f], v2 = mm[b + 512 + f];
  float w0 = mm[b + 128 + f], w1 = mm[b + 384 + f], w2 = mm[b + 640 + f];
  float svw = fmaf(v0, w0, fmaf(v1, w1, v2 * w2));
  size_t gb = (size_t)a * 384;
  float dq = g[gb + f], dmu = g[gb + 128 + f], dqmu = g[gb + 256 + f];
  q[idx] += dq + dqmu * svw;
  size_t mb = (size_t)a * 384;
  mu[mb + f]       += dmu * w0;
  mu[mb + 128 + f] += dmu * w1;
  mu[mb + 256 + f] += dmu * w2;
}

// ---------------- readout: per-molecule segment sum (batch is sorted) ----------------
__global__ __launch_bounds__(128) void readout_kernel(
    const float* __restrict__ q, const int* __restrict__ batch,
    float* __restrict__ out) {
  int m = blockIdx.x;
  int f = threadIdx.x;
  int lo = 0, hi = N_ATOMS;
  while (lo < hi) { int mid = (lo + hi) >> 1; if (batch[mid] < m) lo = mid + 1; else hi = mid; }
  int start = lo;
  hi = N_ATOMS;
  while (lo < hi) { int mid = (lo + hi) >> 1; if (batch[mid] < m + 1) lo = mid + 1; else hi = mid; }
  int end = lo;
  float s = 0.0f;
  for (int a = start; a < end; ++a) s += q[(size_t)a * 128 + f];
  out[(size_t)m * 128 + f] = s;
}

// ---------------- launch ----------------
extern "C" void kernel_launch(void* const* d_in, const int* in_sizes, int n_in,
                              void* d_out, int out_size, void* d_ws, size_t ws_size,
                              hipStream_t stream) {
  const float* pos      = (const float*)d_in[0];
  const float* emb      = (const float*)d_in[1];
  const float* filt_W   = (const float*)d_in[2];
  const float* filt_b   = (const float*)d_in[3];
  const float* inter_W1 = (const float*)d_in[4];
  const float* inter_b1 = (const float*)d_in[5];
  const float* inter_W2 = (const float*)d_in[6];
  const float* inter_b2 = (const float*)d_in[7];
  const float* mix_W1   = (const float*)d_in[8];
  const float* mix_b1   = (const float*)d_in[9];
  const float* mix_W2   = (const float*)d_in[10];
  const float* mix_b2   = (const float*)d_in[11];
  const float* mix_Wmu  = (const float*)d_in[12];
  const int*   x        = (const int*)d_in[13];
  const int*   idx_i    = (const int*)d_in[14];
  const int*   idx_j    = (const int*)d_in[15];
  const int*   batch    = (const int*)d_in[16];
  float* out = (float*)d_out;

  if (ws_size < WS_NEEDED_BYTES) return;  // pure-poison output => ws too small

  float* wsf   = (float*)d_ws;
  float* dirv  = wsf + OFF_DIR;
  float* phi   = wsf + OFF_PHI;
  float* fcutv = wsf + OFF_FCUT;
  float* q     = wsf + OFF_Q;
  float* h     = wsf + OFF_H;     // also g
  float* mu0   = wsf + OFF_MU0;
  float* mu1   = wsf + OFF_MU1;
  float* t     = wsf + OFF_T;     // t and t2
  float* ctx   = wsf + OFF_CTX;
  float* mm    = wsf + OFF_MM;
  int* wsi     = (int*)(wsf + OFF_INT);
  int* counts  = wsi;
  int* cursor  = wsi + N_ATOMS;
  int* row_ptr = wsi + 2 * N_ATOMS;
  int* edge_ord= wsi + 3 * N_ATOMS + 64;

  // edge geometry + CSR
  geom_kernel<<<N_EDGES/256, 256, 0, stream>>>(pos, idx_i, idx_j, dirv, phi, fcutv);
  hipMemsetAsync(counts, 0, 2 * N_ATOMS * sizeof(int), stream);  // counts + cursor
  hist_kernel<<<N_EDGES/256, 256, 0, stream>>>(idx_i, counts);
  scan_kernel<<<1, 256, 0, stream>>>(counts, row_ptr);
  scatter_kernel<<<N_EDGES/256, 256, 0, stream>>>(idx_i, row_ptr, cursor, edge_ord);
  init_kernel<<<N_ATOMS*128/256, 256, 0, stream>>>(x, emb, q, mu0);

  float* mu_c = mu0;
  float* mu_n = mu1;
  for (int l = 0; l < 3; ++l) {
    // h = silu(q @ W1^T + b1) @ W2^T + b2
    gemm_tn<1><<<dim3(128, 2), 256, 0, stream>>>(
        q, inter_W1 + (size_t)l*128*128, inter_b1 + (size_t)l*128, t, 16384, 128, 128);
    gemm_tn<0><<<dim3(128, 6), 256, 0, stream>>>(
        t, inter_W2 + (size_t)l*384*128, inter_b2 + (size_t)l*384, h, 16384, 384, 128);
    // message passing (updates q in place, writes mu_n = mu_c + dmu)
    edge_kernel<<<N_ATOMS/4, 256, 0, stream>>>(
        phi, fcutv, dirv, filt_W, filt_b, h, mu_c, idx_j, row_ptr, edge_ord, q, mu_n);
    // mixing: mm = mu @ Wmu^T  ([3N,128] x [256,128]^T)
    gemm_tn<0><<<dim3(384, 4), 256, 0, stream>>>(
        mu_n, mix_Wmu + (size_t)l*256*128, nullptr, mm, 49152, 256, 128);
    ctx_kernel<<<N_ATOMS*128/256, 256, 0, stream>>>(q, mm, ctx);
    gemm_tn<1><<<dim3(128, 2), 256, 0, stream>>>(
        ctx, mix_W1 + (size_t)l*128*256, mix_b1 + (size_t)l*128, t, 16384, 128, 256);
    gemm_tn<0><<<dim3(128, 6), 256, 0, stream>>>(
        t, mix_W2 + (size_t)l*384*128, mix_b2 + (size_t)l*384, h, 16384, 384, 128);
    mixup_kernel<<<N_ATOMS*128/256, 256, 0, stream>>>(h, mm, q, mu_n);
    float* tmp = mu_c; mu_c = mu_n; mu_n = tmp;
  }
  readout_kernel<<<512, 128, 0, stream>>>(q, batch, out);
}

// Round 6
// 1360.472 us; speedup vs baseline: 1.0924x; 1.0924x over previous
//
#include <hip/hip_runtime.h>

#define N_ATOMS 16384
#define N_EDGES 262144
#define NRBF 20

// ---------------- workspace layout (units of 4 bytes) ----------------
static const size_t OFF_DIR4 = 0;                                // [E][4] (dx,dy,dz,d)
static const size_t OFF_Q    = OFF_DIR4 + (size_t)4*N_EDGES;     // [N][128]
static const size_t OFF_H    = OFF_Q    + (size_t)N_ATOMS*128;   // [N][384] (also g)
static const size_t OFF_MU0  = OFF_H    + (size_t)N_ATOMS*384;   // [N][3][128]
static const size_t OFF_MU1  = OFF_MU0  + (size_t)N_ATOMS*384;
static const size_t OFF_T    = OFF_MU1  + (size_t)N_ATOMS*384;   // [N][128] (t and t2)
static const size_t OFF_CTX  = OFF_T    + (size_t)N_ATOMS*128;   // [N][256]
static const size_t OFF_MM   = OFF_CTX  + (size_t)N_ATOMS*256;   // [N][3][256]
static const size_t OFF_INT  = OFF_MM   + (size_t)N_ATOMS*768;
// counts[N], cursor[N], row_ptr[N+1 (pad to N+64)], edge_ord[E]
static const size_t WS_NEEDED_BYTES =
    (OFF_INT + (size_t)3*N_ATOMS + 64 + (size_t)N_EDGES) * 4;

// ---------------- geometry: unit dir + distance packed as float4 ----------------
__global__ __launch_bounds__(256) void geom_kernel(
    const float* __restrict__ pos, const int* __restrict__ idx_i,
    const int* __restrict__ idx_j, float4* __restrict__ dir4) {
  int e = blockIdx.x * 256 + threadIdx.x;
  int i = idx_i[e], j = idx_j[e];
  float xi = pos[3*i], yi = pos[3*i+1], zi = pos[3*i+2];
  float xj = pos[3*j], yj = pos[3*j+1], zj = pos[3*j+2];
  float dx = xj - xi, dy = yj - yi, dz = zj - zi;
  float d = sqrtf(dx*dx + dy*dy + dz*dz);
  float inv = 1.0f / d;
  dir4[e] = make_float4(dx*inv, dy*inv, dz*inv, d);
}

// ---------------- CSR build ----------------
__global__ __launch_bounds__(256) void hist_kernel(const int* __restrict__ idx_i,
                                                   int* __restrict__ counts) {
  int e = blockIdx.x * 256 + threadIdx.x;
  atomicAdd(&counts[idx_i[e]], 1);
}

__global__ __launch_bounds__(256) void scan_kernel(const int* __restrict__ counts,
                                                   int* __restrict__ row_ptr) {
  __shared__ int part[256];
  int t = threadIdx.x;
  int base = t * 64;
  int s = 0;
  for (int k = 0; k < 64; ++k) s += counts[base + k];
  part[t] = s;
  __syncthreads();
  for (int off = 1; off < 256; off <<= 1) {
    int v = (t >= off) ? part[t - off] : 0;
    __syncthreads();
    part[t] += v;
    __syncthreads();
  }
  int run = (t > 0) ? part[t - 1] : 0;
  for (int k = 0; k < 64; ++k) { row_ptr[base + k] = run; run += counts[base + k]; }
  if (t == 255) row_ptr[N_ATOMS] = run;
}

__global__ __launch_bounds__(256) void scatter_kernel(
    const int* __restrict__ idx_i, const int* __restrict__ row_ptr,
    int* __restrict__ cursor, int* __restrict__ edge_ord) {
  int e = blockIdx.x * 256 + threadIdx.x;
  int i = idx_i[e];
  int p = atomicAdd(&cursor[i], 1);
  edge_ord[row_ptr[i] + p] = e;
}

// ---------------- init: q = emb[x] (mu0 init not needed; layer0 writes mu fully) ----
__global__ __launch_bounds__(256) void init_kernel(
    const int* __restrict__ x, const float* __restrict__ emb,
    float* __restrict__ q) {
  int idx = blockIdx.x * 256 + threadIdx.x;   // over N*128
  int a = idx >> 7, f = idx & 127;
  q[idx] = emb[(size_t)x[a]*128 + f];
}

// ---------------- tiled f32 GEMM: C[M,N] = act(A[M,K] @ B[N,K]^T + bias) ----------------
// BM=128, BN=64, BK=32; 256 threads; 8x4 per-thread tile; A/B staged transposed in LDS.
template <int SILU>
__global__ __launch_bounds__(256) void gemm_tn(
    const float* __restrict__ A, const float* __restrict__ B,
    const float* __restrict__ bias, float* __restrict__ C,
    int M, int N, int K) {
  __shared__ float As[32][132];
  __shared__ float Bs[32][68];
  const int tid = threadIdx.x;
  const int m0 = blockIdx.x * 128;
  const int n0 = blockIdx.y * 64;
  const int tx = tid & 15;        // N dir (16*4 = 64)
  const int ty = tid >> 4;        // M dir (16*8 = 128)
  const int lrow = tid >> 3;      // 0..31
  const int lk4  = (tid & 7) * 4; // 0..28
  float acc[8][4] = {};
  for (int k0 = 0; k0 < K; k0 += 32) {
    __syncthreads();
    #pragma unroll
    for (int r = 0; r < 4; ++r) {
      int row = lrow + 32 * r;
      float4 v = *(const float4*)&A[(size_t)(m0 + row) * K + k0 + lk4];
      As[lk4+0][row] = v.x; As[lk4+1][row] = v.y;
      As[lk4+2][row] = v.z; As[lk4+3][row] = v.w;
    }
    #pragma unroll
    for (int r = 0; r < 2; ++r) {
      int row = lrow + 32 * r;
      float4 v = *(const float4*)&B[(size_t)(n0 + row) * K + k0 + lk4];
      Bs[lk4+0][row] = v.x; Bs[lk4+1][row] = v.y;
      Bs[lk4+2][row] = v.z; Bs[lk4+3][row] = v.w;
    }
    __syncthreads();
    #pragma unroll
    for (int kk = 0; kk < 32; ++kk) {
      float4 a0 = *(const float4*)&As[kk][ty*8];
      float4 a1 = *(const float4*)&As[kk][ty*8+4];
      float4 b0 = *(const float4*)&Bs[kk][tx*4];
      float av[8] = {a0.x,a0.y,a0.z,a0.w,a1.x,a1.y,a1.z,a1.w};
      float bv[4] = {b0.x,b0.y,b0.z,b0.w};
      #pragma unroll
      for (int i = 0; i < 8; ++i)
        #pragma unroll
        for (int j = 0; j < 4; ++j)
          acc[i][j] = fmaf(av[i], bv[j], acc[i][j]);
    }
  }
  #pragma unroll
  for (int i = 0; i < 8; ++i) {
    int m = m0 + ty*8 + i;
    float4 o;
    float* po = &o.x;
    #pragma unroll
    for (int j = 0; j < 4; ++j) {
      int n = n0 + tx*4 + j;
      float c = acc[i][j] + (bias ? bias[n] : 0.0f);
      if (SILU) c = c / (1.0f + expf(-c));
      po[j] = c;
    }
    *(float4*)&C[(size_t)m * N + n0 + tx*4] = o;
  }
}

// ---------------- edge interaction: 2 waves / atom, 1 feature / lane ----------------
// Wave-uniform scalar path for e/j/dir; vector pipe only does coalesced h/mu gathers.
// RBF+fcut recomputed in registers from d (removes 20 random loads per edge).
template <int L0>
__global__ __launch_bounds__(256, 4) void edge_kernel(
    const float4* __restrict__ dir4,
    const float* __restrict__ filtW, const float* __restrict__ filtb,
    const float* __restrict__ h, const float* __restrict__ mu_c,
    const int* __restrict__ idx_j, const int* __restrict__ row_ptr,
    const int* __restrict__ edge_ord,
    float* __restrict__ q, float* __restrict__ mu_n) {
  const int lane = threadIdx.x & 63;
  const int half = (threadIdx.x >> 6) & 1;
  const int slot = __builtin_amdgcn_readfirstlane(threadIdx.x >> 7);  // 0/1, SGPR
  const int a = blockIdx.x * 2 + slot;
  const int f = half * 64 + lane;                     // feature 0..127
  // filter rows f, 128+f, 256+f held in VGPRs (60+3 regs)
  float fw[3][20], fb3[3];
  #pragma unroll
  for (int s = 0; s < 3; ++s) {
    int c = s * 128 + f;
    fb3[s] = filtb[c];
    #pragma unroll
    for (int k = 0; k < 20; ++k) fw[s][k] = filtW[c * 20 + k];
  }
  const int rs = row_ptr[a], re = row_ptr[a + 1];
  float accq = 0.f, am0 = 0.f, am1 = 0.f, am2 = 0.f;
  const float kw = 5.0f / 19.0f;
  const float c2 = (-0.5f / (kw * kw)) * 1.44269504088896340736f;  // coef * log2(e)
  #pragma unroll 2
  for (int t = rs; t < re; ++t) {
    const int e = edge_ord[t];        // t wave-uniform -> scalar loads
    const int j = idx_j[e];
    const float4 dv = dir4[e];
    const float d = dv.w;
    // coalesced gathers (issue early)
    const size_t hb = (size_t)j * 384 + f;
    const float hq = h[hb], hr = h[hb + 128], hm = h[hb + 256];
    float mj0 = 0.f, mj1 = 0.f, mj2 = 0.f;
    if (!L0) {
      mj0 = mu_c[hb]; mj1 = mu_c[hb + 128]; mj2 = mu_c[hb + 256];
    }
    const float fc = (d < 5.0f) ? 0.5f * (cosf(d * 0.62831853071795864769f) + 1.0f) : 0.0f;
    float w0 = fb3[0], w1 = fb3[1], w2 = fb3[2];
    #pragma unroll
    for (int k = 0; k < 20; ++k) {
      float tt = d - kw * (float)k;
      float p = exp2f(c2 * tt * tt);
      w0 = fmaf(p, fw[0][k], w0);
      w1 = fmaf(p, fw[1][k], w1);
      w2 = fmaf(p, fw[2][k], w2);
    }
    w0 *= fc; w1 *= fc; w2 *= fc;
    accq = fmaf(w0, hq, accq);
    const float xr = w1 * hr;
    const float xm = w2 * hm;
    if (!L0) {
      am0 = fmaf(xr, dv.x, fmaf(xm, mj0, am0));
      am1 = fmaf(xr, dv.y, fmaf(xm, mj1, am1));
      am2 = fmaf(xr, dv.z, fmaf(xm, mj2, am2));
    } else {
      am0 = fmaf(xr, dv.x, am0);
      am1 = fmaf(xr, dv.y, am1);
      am2 = fmaf(xr, dv.z, am2);
    }
  }
  q[(size_t)a * 128 + f] += accq;
  const size_t mb = (size_t)a * 384 + f;
  if (L0) {   // mu_c == 0: write dmu directly (also serves as mu init)
    mu_n[mb] = am0; mu_n[mb + 128] = am1; mu_n[mb + 256] = am2;
  } else {
    mu_n[mb]       = mu_c[mb]       + am0;
    mu_n[mb + 128] = mu_c[mb + 128] + am1;
    mu_n[mb + 256] = mu_c[mb + 256] + am2;
  }
}

// ---------------- mixing helpers ----------------
__global__ __launch_bounds__(256) void ctx_kernel(
    const float* __restrict__ q, const float* __restrict__ mm,
    float* __restrict__ ctx) {
  int idx = blockIdx.x * 256 + threadIdx.x;  // over N*128
  int a = idx >> 7, f = idx & 127;
  size_t b = (size_t)a * 768;
  float v0 = mm[b + f], v1 = mm[b + 256 + f], v2 = mm[b + 512 + f];
  float vn = sqrtf(fmaf(v0, v0, fmaf(v1, v1, v2 * v2)) + 1e-8f);
  ctx[(size_t)a * 256 + f] = q[idx];
  ctx[(size_t)a * 256 + 128 + f] = vn;
}

__global__ __launch_bounds__(256) void mixup_kernel(
    const float* __restrict__ g, const float* __restrict__ mm,
    float* __restrict__ q, float* __restrict__ mu) {
  int idx = blockIdx.x * 256 + threadIdx.x;  // over N*128
  int a = idx >> 7, f = idx & 127;
  size_t b = (size_t)a * 768;
  float v0 = mm[b + f],       v1 = mm[b + 256 + f], v2 = mm[b + 512 + f];
  float w0 = mm[b + 128 + f], w1 = mm[b + 384 + f], w2 = mm[b + 640 + f];
  float svw = fmaf(v0, w0, fmaf(v1, w1, v2 * w2));
  size_t gb = (size_t)a * 384;
  float dq = g[gb + f], dmu = g[gb + 128 + f], dqmu = g[gb + 256 + f];
  q[idx] += dq + dqmu * svw;
  size_t mb = (size_t)a * 384;
  mu[mb + f]       += dmu * w0;
  mu[mb + 128 + f] += dmu * w1;
  mu[mb + 256 + f] += dmu * w2;
}

// ---------------- readout: per-molecule segment sum (batch is sorted) ----------------
__global__ __launch_bounds__(128) void readout_kernel(
    const float* __restrict__ q, const int* __restrict__ batch,
    float* __restrict__ out) {
  int m = blockIdx.x;
  int f = threadIdx.x;
  int lo = 0, hi = N_ATOMS;
  while (lo < hi) { int mid = (lo + hi) >> 1; if (batch[mid] < m) lo = mid + 1; else hi = mid; }
  int start = lo;
  hi = N_ATOMS;
  while (lo < hi) { int mid = (lo + hi) >> 1; if (batch[mid] < m + 1) lo = mid + 1; else hi = mid; }
  int end = lo;
  float s = 0.0f;
  for (int a = start; a < end; ++a) s += q[(size_t)a * 128 + f];
  out[(size_t)m * 128 + f] = s;
}

// ---------------- launch ----------------
extern "C" void kernel_launch(void* const* d_in, const int* in_sizes, int n_in,
                              void* d_out, int out_size, void* d_ws, size_t ws_size,
                              hipStream_t stream) {
  const float* pos      = (const float*)d_in[0];
  const float* emb      = (const float*)d_in[1];
  const float* filt_W   = (const float*)d_in[2];
  const float* filt_b   = (const float*)d_in[3];
  const float* inter_W1 = (const float*)d_in[4];
  const float* inter_b1 = (const float*)d_in[5];
  const float* inter_W2 = (const float*)d_in[6];
  const float* inter_b2 = (const float*)d_in[7];
  const float* mix_W1   = (const float*)d_in[8];
  const float* mix_b1   = (const float*)d_in[9];
  const float* mix_W2   = (const float*)d_in[10];
  const float* mix_b2   = (const float*)d_in[11];
  const float* mix_Wmu  = (const float*)d_in[12];
  const int*   x        = (const int*)d_in[13];
  const int*   idx_i    = (const int*)d_in[14];
  const int*   idx_j    = (const int*)d_in[15];
  const int*   batch    = (const int*)d_in[16];
  float* out = (float*)d_out;

  if (ws_size < WS_NEEDED_BYTES) return;  // pure-poison output => ws too small

  float* wsf    = (float*)d_ws;
  float4* dir4  = (float4*)(wsf + OFF_DIR4);
  float* q      = wsf + OFF_Q;
  float* h      = wsf + OFF_H;     // also g
  float* mu0    = wsf + OFF_MU0;
  float* mu1    = wsf + OFF_MU1;
  float* t      = wsf + OFF_T;     // t and t2
  float* ctx    = wsf + OFF_CTX;
  float* mm     = wsf + OFF_MM;
  int* wsi      = (int*)(wsf + OFF_INT);
  int* counts   = wsi;
  int* cursor   = wsi + N_ATOMS;
  int* row_ptr  = wsi + 2 * N_ATOMS;
  int* edge_ord = wsi + 3 * N_ATOMS + 64;

  // edge geometry + CSR
  geom_kernel<<<N_EDGES/256, 256, 0, stream>>>(pos, idx_i, idx_j, dir4);
  hipMemsetAsync(counts, 0, 2 * N_ATOMS * sizeof(int), stream);  // counts + cursor
  hist_kernel<<<N_EDGES/256, 256, 0, stream>>>(idx_i, counts);
  scan_kernel<<<1, 256, 0, stream>>>(counts, row_ptr);
  scatter_kernel<<<N_EDGES/256, 256, 0, stream>>>(idx_i, row_ptr, cursor, edge_ord);
  init_kernel<<<N_ATOMS*128/256, 256, 0, stream>>>(x, emb, q);

  float* mu_c = mu0;
  float* mu_n = mu1;
  for (int l = 0; l < 3; ++l) {
    // h = silu(q @ W1^T + b1) @ W2^T + b2
    gemm_tn<1><<<dim3(128, 2), 256, 0, stream>>>(
        q, inter_W1 + (size_t)l*128*128, inter_b1 + (size_t)l*128, t, 16384, 128, 128);
    gemm_tn<0><<<dim3(128, 6), 256, 0, stream>>>(
        t, inter_W2 + (size_t)l*384*128, inter_b2 + (size_t)l*384, h, 16384, 384, 128);
    // message passing (updates q in place, writes mu_n = mu_c + dmu)
    if (l == 0)
      edge_kernel<1><<<N_ATOMS/2, 256, 0, stream>>>(
          dir4, filt_W, filt_b, h, mu_c, idx_j, row_ptr, edge_ord, q, mu_n);
    else
      edge_kernel<0><<<N_ATOMS/2, 256, 0, stream>>>(
          dir4, filt_W, filt_b, h, mu_c, idx_j, row_ptr, edge_ord, q, mu_n);
    // mixing: mm = mu @ Wmu^T  ([3N,128] x [256,128]^T)
    gemm_tn<0><<<dim3(384, 4), 256, 0, stream>>>(
        mu_n, mix_Wmu + (size_t)l*256*128, nullptr, mm, 49152, 256, 128);
    ctx_kernel<<<N_ATOMS*128/256, 256, 0, stream>>>(q, mm, ctx);
    gemm_tn<1><<<dim3(128, 2), 256, 0, stream>>>(
        ctx, mix_W1 + (size_t)l*128*256, mix_b1 + (size_t)l*128, t, 16384, 128, 256);
    gemm_tn<0><<<dim3(128, 6), 256, 0, stream>>>(
        t, mix_W2 + (size_t)l*384*128, mix_b2 + (size_t)l*384, h, 16384, 384, 128);
    mixup_kernel<<<N_ATOMS*128/256, 256, 0, stream>>>(h, mm, q, mu_n);
    float* tmp = mu_c; mu_c = mu_n; mu_n = tmp;
  }
  readout_kernel<<<512, 128, 0, stream>>>(q, batch, out);
}

// Round 7
// 965.319 us; speedup vs baseline: 1.5395x; 1.4093x over previous
//
#include <hip/hip_runtime.h>

#define N_ATOMS 16384
#define N_EDGES 262144
#define NRBF 20

// ---------------- workspace layout (units of 4 bytes) ----------------
// T (2M floats) doubles as edge_ord (E ints) during setup: edge_ord is dead
// after prep_kernel, T is first written by the layer-0 GEMM afterwards.
static const size_t OFF_T    = 0;                                // [N][128] (t/t2; first E = edge_ord)
static const size_t OFF_REC  = OFF_T   + (size_t)N_ATOMS*128;    // [E][25] CSR-ordered edge records
static const size_t OFF_Q    = OFF_REC + (size_t)25*N_EDGES;     // [N][128]
static const size_t OFF_H    = OFF_Q   + (size_t)N_ATOMS*128;    // [N][384] (also g)
static const size_t OFF_MU0  = OFF_H   + (size_t)N_ATOMS*384;    // [N][3][128]
static const size_t OFF_MU1  = OFF_MU0 + (size_t)N_ATOMS*384;
static const size_t OFF_CTX  = OFF_MU1 + (size_t)N_ATOMS*384;    // [N][256]
static const size_t OFF_MM   = OFF_CTX + (size_t)N_ATOMS*256;    // [N][3][256]
static const size_t OFF_INT  = OFF_MM  + (size_t)N_ATOMS*768;    // counts[N], cursor[N], row_ptr[N+64]
static const size_t WS_NEEDED_BYTES = (OFF_INT + (size_t)3*N_ATOMS + 64) * 4;  // == 185794816 (proven)

// ---------------- CSR build ----------------
__global__ __launch_bounds__(256) void hist_kernel(const int* __restrict__ idx_i,
                                                   int* __restrict__ counts) {
  int e = blockIdx.x * 256 + threadIdx.x;
  atomicAdd(&counts[idx_i[e]], 1);
}

__global__ __launch_bounds__(256) void scan_kernel(const int* __restrict__ counts,
                                                   int* __restrict__ row_ptr) {
  __shared__ int part[256];
  int t = threadIdx.x;
  int base = t * 64;
  int s = 0;
  for (int k = 0; k < 64; ++k) s += counts[base + k];
  part[t] = s;
  __syncthreads();
  for (int off = 1; off < 256; off <<= 1) {
    int v = (t >= off) ? part[t - off] : 0;
    __syncthreads();
    part[t] += v;
    __syncthreads();
  }
  int run = (t > 0) ? part[t - 1] : 0;
  for (int k = 0; k < 64; ++k) { row_ptr[base + k] = run; run += counts[base + k]; }
  if (t == 255) row_ptr[N_ATOMS] = run;
}

__global__ __launch_bounds__(256) void scatter_kernel(
    const int* __restrict__ idx_i, const int* __restrict__ row_ptr,
    int* __restrict__ cursor, int* __restrict__ edge_ord) {
  int e = blockIdx.x * 256 + threadIdx.x;
  int i = idx_i[e];
  int p = atomicAdd(&cursor[i], 1);
  edge_ord[row_ptr[i] + p] = e;
}

// ---------------- prep: per CSR slot, all wave-uniform edge math, once ----------------
// record[t][0..24] = [j, dx, dy, dz, fc, fc*phi_0 .. fc*phi_19]
__global__ __launch_bounds__(256) void prep_kernel(
    const float* __restrict__ pos, const int* __restrict__ idx_i,
    const int* __restrict__ idx_j, const int* __restrict__ edge_ord,
    float* __restrict__ rec) {
  int t = blockIdx.x * 256 + threadIdx.x;
  int e = edge_ord[t];
  int i = idx_i[e], j = idx_j[e];
  float xi = pos[3*i], yi = pos[3*i+1], zi = pos[3*i+2];
  float xj = pos[3*j], yj = pos[3*j+1], zj = pos[3*j+2];
  float dx = xj - xi, dy = yj - yi, dz = zj - zi;
  float d = sqrtf(dx*dx + dy*dy + dz*dz);
  float inv = 1.0f / d;
  float fc = (d < 5.0f) ? 0.5f * (cosf(d * 0.62831853071795864769f) + 1.0f) : 0.0f;
  float* r = rec + (size_t)t * 25;
  r[0] = __int_as_float(j);
  r[1] = dx * inv; r[2] = dy * inv; r[3] = dz * inv; r[4] = fc;
  const float kw = 5.0f / 19.0f;
  const float c2 = (-0.5f / (kw * kw)) * 1.44269504088896340736f;  // coef * log2(e)
  #pragma unroll
  for (int k = 0; k < NRBF; ++k) {
    float tt = d - kw * (float)k;
    r[5 + k] = fc * exp2f(c2 * tt * tt);
  }
}

// ---------------- init: q = emb[x] (mu init not needed; layer0 writes mu fully) ----
__global__ __launch_bounds__(256) void init_kernel(
    const int* __restrict__ x, const float* __restrict__ emb,
    float* __restrict__ q) {
  int idx = blockIdx.x * 256 + threadIdx.x;   // over N*128
  int a = idx >> 7, f = idx & 127;
  q[idx] = emb[(size_t)x[a]*128 + f];
}

// ---------------- tiled f32 GEMM: C[M,N] = act(A[M,K] @ B[N,K]^T + bias) ----------------
// BM=128, BN=64, BK=32; 256 threads; 8x4 per-thread tile; A/B staged transposed in LDS.
template <int SILU>
__global__ __launch_bounds__(256) void gemm_tn(
    const float* __restrict__ A, const float* __restrict__ B,
    const float* __restrict__ bias, float* __restrict__ C,
    int M, int N, int K) {
  __shared__ float As[32][132];
  __shared__ float Bs[32][68];
  const int tid = threadIdx.x;
  const int m0 = blockIdx.x * 128;
  const int n0 = blockIdx.y * 64;
  const int tx = tid & 15;        // N dir (16*4 = 64)
  const int ty = tid >> 4;        // M dir (16*8 = 128)
  const int lrow = tid >> 3;      // 0..31
  const int lk4  = (tid & 7) * 4; // 0..28
  float acc[8][4] = {};
  for (int k0 = 0; k0 < K; k0 += 32) {
    __syncthreads();
    #pragma unroll
    for (int r = 0; r < 4; ++r) {
      int row = lrow + 32 * r;
      float4 v = *(const float4*)&A[(size_t)(m0 + row) * K + k0 + lk4];
      As[lk4+0][row] = v.x; As[lk4+1][row] = v.y;
      As[lk4+2][row] = v.z; As[lk4+3][row] = v.w;
    }
    #pragma unroll
    for (int r = 0; r < 2; ++r) {
      int row = lrow + 32 * r;
      float4 v = *(const float4*)&B[(size_t)(n0 + row) * K + k0 + lk4];
      Bs[lk4+0][row] = v.x; Bs[lk4+1][row] = v.y;
      Bs[lk4+2][row] = v.z; Bs[lk4+3][row] = v.w;
    }
    __syncthreads();
    #pragma unroll
    for (int kk = 0; kk < 32; ++kk) {
      float4 a0 = *(const float4*)&As[kk][ty*8];
      float4 a1 = *(const float4*)&As[kk][ty*8+4];
      float4 b0 = *(const float4*)&Bs[kk][tx*4];
      float av[8] = {a0.x,a0.y,a0.z,a0.w,a1.x,a1.y,a1.z,a1.w};
      float bv[4] = {b0.x,b0.y,b0.z,b0.w};
      #pragma unroll
      for (int i = 0; i < 8; ++i)
        #pragma unroll
        for (int j = 0; j < 4; ++j)
          acc[i][j] = fmaf(av[i], bv[j], acc[i][j]);
    }
  }
  #pragma unroll
  for (int i = 0; i < 8; ++i) {
    int m = m0 + ty*8 + i;
    float4 o;
    float* po = &o.x;
    #pragma unroll
    for (int j = 0; j < 4; ++j) {
      int n = n0 + tx*4 + j;
      float c = acc[i][j] + (bias ? bias[n] : 0.0f);
      if (SILU) c = c / (1.0f + expf(-c));
      po[j] = c;
    }
    *(float4*)&C[(size_t)m * N + n0 + tx*4] = o;
  }
}

// ---------------- edge interaction: 2 waves / atom, 1 feature / lane ----------------
// All wave-uniform math precomputed in rec (scalar sequential reads); hot loop is
// 63 FMA (scalar pp x VGPR fw) + coalesced h/mu gathers. No transcendentals.
template <int L0>
__global__ __launch_bounds__(256, 4) void edge_kernel(
    const float* __restrict__ rec,
    const float* __restrict__ filtW, const float* __restrict__ filtb,
    const float* __restrict__ h, const float* __restrict__ mu_c,
    const int* __restrict__ row_ptr,
    float* __restrict__ q, float* __restrict__ mu_n) {
  const int lane = threadIdx.x & 63;
  const int half = (threadIdx.x >> 6) & 1;
  const int slot = __builtin_amdgcn_readfirstlane(threadIdx.x >> 7);  // 0/1, SGPR
  const int a = blockIdx.x * 2 + slot;
  const int f = half * 64 + lane;                     // feature 0..127
  // filter rows f, 128+f, 256+f held in VGPRs (60+3 regs)
  float fw[3][20], fb3[3];
  #pragma unroll
  for (int s = 0; s < 3; ++s) {
    int c = s * 128 + f;
    fb3[s] = filtb[c];
    #pragma unroll
    for (int k = 0; k < 20; ++k) fw[s][k] = filtW[c * 20 + k];
  }
  const int rs = row_ptr[a], re = row_ptr[a + 1];
  float accq = 0.f, am0 = 0.f, am1 = 0.f, am2 = 0.f;
  #pragma unroll 2
  for (int t = rs; t < re; ++t) {
    const float* r = rec + (size_t)t * 25;            // t wave-uniform -> scalar loads
    const int j = __float_as_int(r[0]);
    const float dx = r[1], dy = r[2], dz = r[3], fc = r[4];
    const size_t hb = (size_t)j * 384 + f;
    const float hq = h[hb], hr = h[hb + 128], hm = h[hb + 256];
    float mj0 = 0.f, mj1 = 0.f, mj2 = 0.f;
    if (!L0) {
      mj0 = mu_c[hb]; mj1 = mu_c[hb + 128]; mj2 = mu_c[hb + 256];
    }
    float w0 = fc * fb3[0], w1 = fc * fb3[1], w2 = fc * fb3[2];
    #pragma unroll
    for (int k = 0; k < 20; ++k) {
      const float p = r[5 + k];                       // scalar operand
      w0 = fmaf(p, fw[0][k], w0);
      w1 = fmaf(p, fw[1][k], w1);
      w2 = fmaf(p, fw[2][k], w2);
    }
    accq = fmaf(w0, hq, accq);
    const float xr = w1 * hr;
    const float xm = w2 * hm;
    if (!L0) {
      am0 = fmaf(xr, dx, fmaf(xm, mj0, am0));
      am1 = fmaf(xr, dy, fmaf(xm, mj1, am1));
      am2 = fmaf(xr, dz, fmaf(xm, mj2, am2));
    } else {
      am0 = fmaf(xr, dx, am0);
      am1 = fmaf(xr, dy, am1);
      am2 = fmaf(xr, dz, am2);
    }
  }
  q[(size_t)a * 128 + f] += accq;
  const size_t mb = (size_t)a * 384 + f;
  if (L0) {   // mu_c == 0: write dmu directly (also serves as mu init)
    mu_n[mb] = am0; mu_n[mb + 128] = am1; mu_n[mb + 256] = am2;
  } else {
    mu_n[mb]       = mu_c[mb]       + am0;
    mu_n[mb + 128] = mu_c[mb + 128] + am1;
    mu_n[mb + 256] = mu_c[mb + 256] + am2;
  }
}

// ---------------- mixing helpers ----------------
__global__ __launch_bounds__(256) void ctx_kernel(
    const float* __restrict__ q, const float* __restrict__ mm,
    float* __restrict__ ctx) {
  int idx = blockIdx.x * 256 + threadIdx.x;  // over N*128
  int a = idx >> 7, f = idx & 127;
  size_t b = (size_t)a * 768;
  float v0 = mm[b + f], v1 = mm[b + 256 + f], v2 = mm[b + 512 + f];
  float vn = sqrtf(fmaf(v0, v0, fmaf(v1, v1, v2 * v2)) + 1e-8f);
  ctx[(size_t)a * 256 + f] = q[idx];
  ctx[(size_t)a * 256 + 128 + f] = vn;
}

__global__ __launch_bounds__(256) void mixup_kernel(
    const float* __restrict__ g, const float* __restrict__ mm,
    float* __restrict__ q, float* __restrict__ mu) {
  int idx = blockIdx.x * 256 + threadIdx.x;  // over N*128
  int a = idx >> 7, f = idx & 127;
  size_t b = (size_t)a * 768;
  float v0 = mm[b + f],       v1 = mm[b + 256 + f], v2 = mm[b + 512 + f];
  float w0 = mm[b + 128 + f], w1 = mm[b + 384 + f], w2 = mm[b + 640 + f];
  float svw = fmaf(v0, w0, fmaf(v1, w1, v2 * w2));
  size_t gb = (size_t)a * 384;
  float dq = g[gb + f], dmu = g[gb + 128 + f], dqmu = g[gb + 256 + f];
  q[idx] += dq + dqmu * svw;
  size_t mb = (size_t)a * 384;
  mu[mb + f]       += dmu * w0;
  mu[mb + 128 + f] += dmu * w1;
  mu[mb + 256 + f] += dmu * w2;
}

// ---------------- readout: per-molecule segment sum (batch is sorted) ----------------
__global__ __launch_bounds__(128) void readout_kernel(
    const float* __restrict__ q, const int* __restrict__ batch,
    float* __restrict__ out) {
  int m = blockIdx.x;
  int f = threadIdx.x;
  int lo = 0, hi = N_ATOMS;
  while (lo < hi) { int mid = (lo + hi) >> 1; if (batch[mid] < m) lo = mid + 1; else hi = mid; }
  int start = lo;
  hi = N_ATOMS;
  while (lo < hi) { int mid = (lo + hi) >> 1; if (batch[mid] < m + 1) lo = mid + 1; else hi = mid; }
  int end = lo;
  float s = 0.0f;
  for (int a = start; a < end; ++a) s += q[(size_t)a * 128 + f];
  out[(size_t)m * 128 + f] = s;
}

// ---------------- launch ----------------
extern "C" void kernel_launch(void* const* d_in, const int* in_sizes, int n_in,
                              void* d_out, int out_size, void* d_ws, size_t ws_size,
                              hipStream_t stream) {
  const float* pos      = (const float*)d_in[0];
  const float* emb      = (const float*)d_in[1];
  const float* filt_W   = (const float*)d_in[2];
  const float* filt_b   = (const float*)d_in[3];
  const float* inter_W1 = (const float*)d_in[4];
  const float* inter_b1 = (const float*)d_in[5];
  const float* inter_W2 = (const float*)d_in[6];
  const float* inter_b2 = (const float*)d_in[7];
  const float* mix_W1   = (const float*)d_in[8];
  const float* mix_b1   = (const float*)d_in[9];
  const float* mix_W2   = (const float*)d_in[10];
  const float* mix_b2   = (const float*)d_in[11];
  const float* mix_Wmu  = (const float*)d_in[12];
  const int*   x        = (const int*)d_in[13];
  const int*   idx_i    = (const int*)d_in[14];
  const int*   idx_j    = (const int*)d_in[15];
  const int*   batch    = (const int*)d_in[16];
  float* out = (float*)d_out;

  if (ws_size < WS_NEEDED_BYTES) return;  // pure-poison output => ws too small

  float* wsf    = (float*)d_ws;
  float* t      = wsf + OFF_T;     // t and t2; first E ints = edge_ord during setup
  float* rec    = wsf + OFF_REC;
  float* q      = wsf + OFF_Q;
  float* h      = wsf + OFF_H;     // also g
  float* mu0    = wsf + OFF_MU0;
  float* mu1    = wsf + OFF_MU1;
  float* ctx    = wsf + OFF_CTX;
  float* mm     = wsf + OFF_MM;
  int* wsi      = (int*)(wsf + OFF_INT);
  int* counts   = wsi;
  int* cursor   = wsi + N_ATOMS;
  int* row_ptr  = wsi + 2 * N_ATOMS;
  int* edge_ord = (int*)t;         // aliased; dead after prep_kernel

  // CSR + edge records
  hipMemsetAsync(counts, 0, 2 * N_ATOMS * sizeof(int), stream);  // counts + cursor
  hist_kernel<<<N_EDGES/256, 256, 0, stream>>>(idx_i, counts);
  scan_kernel<<<1, 256, 0, stream>>>(counts, row_ptr);
  scatter_kernel<<<N_EDGES/256, 256, 0, stream>>>(idx_i, row_ptr, cursor, edge_ord);
  prep_kernel<<<N_EDGES/256, 256, 0, stream>>>(pos, idx_i, idx_j, edge_ord, rec);
  init_kernel<<<N_ATOMS*128/256, 256, 0, stream>>>(x, emb, q);

  float* mu_c = mu0;
  float* mu_n = mu1;
  for (int l = 0; l < 3; ++l) {
    // h = silu(q @ W1^T + b1) @ W2^T + b2
    gemm_tn<1><<<dim3(128, 2), 256, 0, stream>>>(
        q, inter_W1 + (size_t)l*128*128, inter_b1 + (size_t)l*128, t, 16384, 128, 128);
    gemm_tn<0><<<dim3(128, 6), 256, 0, stream>>>(
        t, inter_W2 + (size_t)l*384*128, inter_b2 + (size_t)l*384, h, 16384, 384, 128);
    // message passing (updates q in place, writes mu_n = mu_c + dmu)
    if (l == 0)
      edge_kernel<1><<<N_ATOMS/2, 256, 0, stream>>>(
          rec, filt_W, filt_b, h, mu_c, row_ptr, q, mu_n);
    else
      edge_kernel<0><<<N_ATOMS/2, 256, 0, stream>>>(
          rec, filt_W, filt_b, h, mu_c, row_ptr, q, mu_n);
    // mixing: mm = mu @ Wmu^T  ([3N,128] x [256,128]^T)
    gemm_tn<0><<<dim3(384, 4), 256, 0, stream>>>(
        mu_n, mix_Wmu + (size_t)l*256*128, nullptr, mm, 49152, 256, 128);
    ctx_kernel<<<N_ATOMS*128/256, 256, 0, stream>>>(q, mm, ctx);
    gemm_tn<1><<<dim3(128, 2), 256, 0, stream>>>(
        ctx, mix_W1 + (size_t)l*128*256, mix_b1 + (size_t)l*128, t, 16384, 128, 256);
    gemm_tn<0><<<dim3(128, 6), 256, 0, stream>>>(
        t, mix_W2 + (size_t)l*384*128, mix_b2 + (size_t)l*384, h, 16384, 384, 128);
    mixup_kernel<<<N_ATOMS*128/256, 256, 0, stream>>>(h, mm, q, mu_n);
    float* tmp = mu_c; mu_c = mu_n; mu_n = tmp;
  }
  readout_kernel<<<512, 128, 0, stream>>>(q, batch, out);
}

// Round 9
// 773.936 us; speedup vs baseline: 1.9202x; 1.2473x over previous
//
#include <hip/hip_runtime.h>

#define N_ATOMS 16384
#define N_EDGES 262144
#define NRBF 20

typedef __bf16 bf16x8 __attribute__((ext_vector_type(8)));
typedef __bf16 bf16x4 __attribute__((ext_vector_type(4)));
typedef float f32x4 __attribute__((ext_vector_type(4)));

// ---------------- workspace layout (units of 4 bytes) ----------------
// T (2M floats) doubles as edge_ord (E ints) during setup: edge_ord is dead
// after prep_kernel, T is first written by the layer-0 GEMM afterwards.
static const size_t OFF_T    = 0;                                // [N][128] (t/t2; first E = edge_ord)
static const size_t OFF_REC  = OFF_T   + (size_t)N_ATOMS*128;    // [E][25] CSR-ordered edge records
static const size_t OFF_Q    = OFF_REC + (size_t)25*N_EDGES;     // [N][128]
static const size_t OFF_H    = OFF_Q   + (size_t)N_ATOMS*128;    // [N][384] (also g)
static const size_t OFF_MU0  = OFF_H   + (size_t)N_ATOMS*384;    // [N][3][128]
static const size_t OFF_MU1  = OFF_MU0 + (size_t)N_ATOMS*384;
static const size_t OFF_CTX  = OFF_MU1 + (size_t)N_ATOMS*384;    // [N][256]
static const size_t OFF_MM   = OFF_CTX + (size_t)N_ATOMS*256;    // [N][3][256]
static const size_t OFF_INT  = OFF_MM  + (size_t)N_ATOMS*768;    // counts[N], cursor[N], row_ptr[N+64]
static const size_t WS_NEEDED_BYTES = (OFF_INT + (size_t)3*N_ATOMS + 64) * 4;  // == 185794816 (proven)

// ---------------- CSR build ----------------
__global__ __launch_bounds__(256) void hist_kernel(const int* __restrict__ idx_i,
                                                   int* __restrict__ counts) {
  int e = blockIdx.x * 256 + threadIdx.x;
  atomicAdd(&counts[idx_i[e]], 1);
}

__global__ __launch_bounds__(256) void scan_kernel(const int* __restrict__ counts,
                                                   int* __restrict__ row_ptr) {
  __shared__ int part[256];
  int t = threadIdx.x;
  int base = t * 64;
  int s = 0;
  for (int k = 0; k < 64; ++k) s += counts[base + k];
  part[t] = s;
  __syncthreads();
  for (int off = 1; off < 256; off <<= 1) {
    int v = (t >= off) ? part[t - off] : 0;
    __syncthreads();
    part[t] += v;
    __syncthreads();
  }
  int run = (t > 0) ? part[t - 1] : 0;
  for (int k = 0; k < 64; ++k) { row_ptr[base + k] = run; run += counts[base + k]; }
  if (t == 255) row_ptr[N_ATOMS] = run;
}

__global__ __launch_bounds__(256) void scatter_kernel(
    const int* __restrict__ idx_i, const int* __restrict__ row_ptr,
    int* __restrict__ cursor, int* __restrict__ edge_ord) {
  int e = blockIdx.x * 256 + threadIdx.x;
  int i = idx_i[e];
  int p = atomicAdd(&cursor[i], 1);
  edge_ord[row_ptr[i] + p] = e;
}

// ---------------- prep: per CSR slot, all wave-uniform edge math, once ----------------
// record[t][0..24] = [j, dx, dy, dz, fc, fc*phi_0 .. fc*phi_19]
__global__ __launch_bounds__(256) void prep_kernel(
    const float* __restrict__ pos, const int* __restrict__ idx_i,
    const int* __restrict__ idx_j, const int* __restrict__ edge_ord,
    float* __restrict__ rec) {
  int t = blockIdx.x * 256 + threadIdx.x;
  int e = edge_ord[t];
  int i = idx_i[e], j = idx_j[e];
  float xi = pos[3*i], yi = pos[3*i+1], zi = pos[3*i+2];
  float xj = pos[3*j], yj = pos[3*j+1], zj = pos[3*j+2];
  float dx = xj - xi, dy = yj - yi, dz = zj - zi;
  float d = sqrtf(dx*dx + dy*dy + dz*dz);
  float inv = 1.0f / d;
  float fc = (d < 5.0f) ? 0.5f * (cosf(d * 0.62831853071795864769f) + 1.0f) : 0.0f;
  float* r = rec + (size_t)t * 25;
  r[0] = __int_as_float(j);
  r[1] = dx * inv; r[2] = dy * inv; r[3] = dz * inv; r[4] = fc;
  const float kw = 5.0f / 19.0f;
  const float c2 = (-0.5f / (kw * kw)) * 1.44269504088896340736f;  // coef * log2(e)
  #pragma unroll
  for (int k = 0; k < NRBF; ++k) {
    float tt = d - kw * (float)k;
    r[5 + k] = fc * exp2f(c2 * tt * tt);
  }
}

// ---------------- init: q = emb[x] (mu init not needed; layer0 writes mu fully) ----
__global__ __launch_bounds__(256) void init_kernel(
    const int* __restrict__ x, const float* __restrict__ emb,
    float* __restrict__ q) {
  int idx = blockIdx.x * 256 + threadIdx.x;   // over N*128
  int a = idx >> 7, f = idx & 127;
  q[idx] = emb[(size_t)x[a]*128 + f];
}

// ------------- split-bf16 MFMA GEMM: C[M,N] = act(A[M,K] @ B[N,K]^T + bias) -------------
// f32 in/out; in-kernel split A=Ah+Al, B=Bh+Bl (bf16); C = Ah*Bh + Ah*Bl + Al*Bh (f32 acc).
// 256 thr = 4 waves (2x2); BM=128 BN=64 BK=32; wave tile 64x32 = 4x2 frags of 16x16x32.
template <int SILU>
__global__ __launch_bounds__(256) void gemm_mfma(
    const float* __restrict__ A, const float* __restrict__ B,
    const float* __restrict__ bias, float* __restrict__ C,
    int M, int N, int K) {
  __shared__ __bf16 Ah[128][40];   // rows padded to 40 bf16 (80 B = 5*16B)
  __shared__ __bf16 Al[128][40];
  __shared__ __bf16 Bh[64][40];
  __shared__ __bf16 Bl[64][40];
  const int tid  = threadIdx.x;
  const int lane = tid & 63;
  const int w    = tid >> 6;       // wave 0..3
  const int wm   = (w >> 1) * 64;  // wave m-slab within block
  const int wn   = (w & 1) * 32;   // wave n-slab
  const int m0 = blockIdx.x * 128;
  const int n0 = blockIdx.y * 64;
  const int srow = tid >> 3;       // staging row 0..31
  const int skc  = (tid & 7) * 4;  // staging k 0..28
  f32x4 acc[4][2] = {};
  for (int k0 = 0; k0 < K; k0 += 32) {
    __syncthreads();
    #pragma unroll
    for (int it = 0; it < 4; ++it) {          // A: 128 rows
      int row = srow + 32 * it;
      float4 v = *(const float4*)&A[(size_t)(m0 + row) * K + k0 + skc];
      bf16x4 hv, lv;
      float vv[4] = {v.x, v.y, v.z, v.w};
      #pragma unroll
      for (int jj = 0; jj < 4; ++jj) {
        __bf16 hb = (__bf16)vv[jj];
        hv[jj] = hb;
        lv[jj] = (__bf16)(vv[jj] - (float)hb);
      }
      *(bf16x4*)&Ah[row][skc] = hv;
      *(bf16x4*)&Al[row][skc] = lv;
    }
    #pragma unroll
    for (int it = 0; it < 2; ++it) {          // B: 64 rows
      int row = srow + 32 * it;
      float4 v = *(const float4*)&B[(size_t)(n0 + row) * K + k0 + skc];
      bf16x4 hv, lv;
      float vv[4] = {v.x, v.y, v.z, v.w};
      #pragma unroll
      for (int jj = 0; jj < 4; ++jj) {
        __bf16 hb = (__bf16)vv[jj];
        hv[jj] = hb;
        lv[jj] = (__bf16)(vv[jj] - (float)hb);
      }
      *(bf16x4*)&Bh[row][skc] = hv;
      *(bf16x4*)&Bl[row][skc] = lv;
    }
    __syncthreads();
    // fragment loads: lane l -> row (l&15), k = 8*(l>>4)+[0..7] (16B contiguous)
    const int fr = lane & 15;
    const int fk = (lane >> 4) * 8;
    bf16x8 ah[4], al[4], bh[2], bl[2];
    #pragma unroll
    for (int mi = 0; mi < 4; ++mi) {
      ah[mi] = *(const bf16x8*)&Ah[wm + mi*16 + fr][fk];
      al[mi] = *(const bf16x8*)&Al[wm + mi*16 + fr][fk];
    }
    #pragma unroll
    for (int ni = 0; ni < 2; ++ni) {
      bh[ni] = *(const bf16x8*)&Bh[wn + ni*16 + fr][fk];
      bl[ni] = *(const bf16x8*)&Bl[wn + ni*16 + fr][fk];
    }
    #pragma unroll
    for (int mi = 0; mi < 4; ++mi)
      #pragma unroll
      for (int ni = 0; ni < 2; ++ni) {
        acc[mi][ni] = __builtin_amdgcn_mfma_f32_16x16x32_bf16(ah[mi], bh[ni], acc[mi][ni], 0, 0, 0);
        acc[mi][ni] = __builtin_amdgcn_mfma_f32_16x16x32_bf16(ah[mi], bl[ni], acc[mi][ni], 0, 0, 0);
        acc[mi][ni] = __builtin_amdgcn_mfma_f32_16x16x32_bf16(al[mi], bh[ni], acc[mi][ni], 0, 0, 0);
      }
  }
  // epilogue: C col = lane&15, row = 4*(lane>>4)+reg  [m89 layout]
  const int cn = lane & 15;
  const int cr = (lane >> 4) * 4;
  #pragma unroll
  for (int mi = 0; mi < 4; ++mi)
    #pragma unroll
    for (int ni = 0; ni < 2; ++ni) {
      int n = n0 + wn + ni*16 + cn;
      float bb = bias ? bias[n] : 0.0f;
      #pragma unroll
      for (int r = 0; r < 4; ++r) {
        int m = m0 + wm + mi*16 + cr + r;
        float c = acc[mi][ni][r] + bb;
        if (SILU) c = c / (1.0f + expf(-c));
        C[(size_t)m * N + n] = c;
      }
    }
}

// ---------------- edge interaction: 2 waves / atom, 1 feature / lane ----------------
// All wave-uniform math precomputed in rec (scalar sequential reads); hot loop is
// 63 FMA (scalar pp x VGPR fw) + coalesced h/mu gathers. No transcendentals.
template <int L0>
__global__ __launch_bounds__(256, 4) void edge_kernel(
    const float* __restrict__ rec,
    const float* __restrict__ filtW, const float* __restrict__ filtb,
    const float* __restrict__ h, const float* __restrict__ mu_c,
    const int* __restrict__ row_ptr,
    float* __restrict__ q, float* __restrict__ mu_n) {
  const int lane = threadIdx.x & 63;
  const int half = (threadIdx.x >> 6) & 1;
  const int slot = __builtin_amdgcn_readfirstlane(threadIdx.x >> 7);  // 0/1, SGPR
  const int a = blockIdx.x * 2 + slot;
  const int f = half * 64 + lane;                     // feature 0..127
  // filter rows f, 128+f, 256+f held in VGPRs (60+3 regs)
  float fw[3][20], fb3[3];
  #pragma unroll
  for (int s = 0; s < 3; ++s) {
    int c = s * 128 + f;
    fb3[s] = filtb[c];
    #pragma unroll
    for (int k = 0; k < 20; ++k) fw[s][k] = filtW[c * 20 + k];
  }
  const int rs = row_ptr[a], re = row_ptr[a + 1];
  float accq = 0.f, am0 = 0.f, am1 = 0.f, am2 = 0.f;
  #pragma unroll 2
  for (int t = rs; t < re; ++t) {
    const float* r = rec + (size_t)t * 25;            // t wave-uniform -> scalar loads
    const int j = __float_as_int(r[0]);
    const float dx = r[1], dy = r[2], dz = r[3], fc = r[4];
    const size_t hb = (size_t)j * 384 + f;
    const float hq = h[hb], hr = h[hb + 128], hm = h[hb + 256];
    float mj0 = 0.f, mj1 = 0.f, mj2 = 0.f;
    if (!L0) {
      mj0 = mu_c[hb]; mj1 = mu_c[hb + 128]; mj2 = mu_c[hb + 256];
    }
    float w0 = fc * fb3[0], w1 = fc * fb3[1], w2 = fc * fb3[2];
    #pragma unroll
    for (int k = 0; k < 20; ++k) {
      const float p = r[5 + k];                       // scalar operand
      w0 = fmaf(p, fw[0][k], w0);
      w1 = fmaf(p, fw[1][k], w1);
      w2 = fmaf(p, fw[2][k], w2);
    }
    accq = fmaf(w0, hq, accq);
    const float xr = w1 * hr;
    const float xm = w2 * hm;
    if (!L0) {
      am0 = fmaf(xr, dx, fmaf(xm, mj0, am0));
      am1 = fmaf(xr, dy, fmaf(xm, mj1, am1));
      am2 = fmaf(xr, dz, fmaf(xm, mj2, am2));
    } else {
      am0 = fmaf(xr, dx, am0);
      am1 = fmaf(xr, dy, am1);
      am2 = fmaf(xr, dz, am2);
    }
  }
  q[(size_t)a * 128 + f] += accq;
  const size_t mb = (size_t)a * 384 + f;
  if (L0) {   // mu_c == 0: write dmu directly (also serves as mu init)
    mu_n[mb] = am0; mu_n[mb + 128] = am1; mu_n[mb + 256] = am2;
  } else {
    mu_n[mb]       = mu_c[mb]       + am0;
    mu_n[mb + 128] = mu_c[mb + 128] + am1;
    mu_n[mb + 256] = mu_c[mb + 256] + am2;
  }
}

// ---------------- mixing helpers ----------------
__global__ __launch_bounds__(256) void ctx_kernel(
    const float* __restrict__ q, const float* __restrict__ mm,
    float* __restrict__ ctx) {
  int idx = blockIdx.x * 256 + threadIdx.x;  // over N*128
  int a = idx >> 7, f = idx & 127;
  size_t b = (size_t)a * 768;
  float v0 = mm[b + f], v1 = mm[b + 256 + f], v2 = mm[b + 512 + f];
  float vn = sqrtf(fmaf(v0, v0, fmaf(v1, v1, v2 * v2)) + 1e-8f);
  ctx[(size_t)a * 256 + f] = q[idx];
  ctx[(size_t)a * 256 + 128 + f] = vn;
}

__global__ __launch_bounds__(256) void mixup_kernel(
    const float* __restrict__ g, const float* __restrict__ mm,
    float* __restrict__ q, float* __restrict__ mu) {
  int idx = blockIdx.x * 256 + threadIdx.x;  // over N*128
  int a = idx >> 7, f = idx & 127;
  size_t b = (size_t)a * 768;
  float v0 = mm[b + f],       v1 = mm[b + 256 + f], v2 = mm[b + 512 + f];
  float w0 = mm[b + 128 + f], w1 = mm[b + 384 + f], w2 = mm[b + 640 + f];
  float svw = fmaf(v0, w0, fmaf(v1, w1, v2 * w2));
  size_t gb = (size_t)a * 384;
  float dq = g[gb + f], dmu = g[gb + 128 + f], dqmu = g[gb + 256 + f];
  q[idx] += dq + dqmu * svw;
  size_t mb = (size_t)a * 384;
  mu[mb + f]       += dmu * w0;
  mu[mb + 128 + f] += dmu * w1;
  mu[mb + 256 + f] += dmu * w2;
}

// ---------------- readout: per-molecule segment sum (batch is sorted) ----------------
__global__ __launch_bounds__(128) void readout_kernel(
    const float* __restrict__ q, const int* __restrict__ batch,
    float* __restrict__ out) {
  int m = blockIdx.x;
  int f = threadIdx.x;
  int lo = 0, hi = N_ATOMS;
  while (lo < hi) { int mid = (lo + hi) >> 1; if (batch[mid] < m) lo = mid + 1; else hi = mid; }
  int start = lo;
  hi = N_ATOMS;
  while (lo < hi) { int mid = (lo + hi) >> 1; if (batch[mid] < m + 1) lo = mid + 1; else hi = mid; }
  int end = lo;
  float s = 0.0f;
  for (int a = start; a < end; ++a) s += q[(size_t)a * 128 + f];
  out[(size_t)m * 128 + f] = s;
}

// ---------------- launch ----------------
extern "C" void kernel_launch(void* const* d_in, const int* in_sizes, int n_in,
                              void* d_out, int out_size, void* d_ws, size_t ws_size,
                              hipStream_t stream) {
  const float* pos      = (const float*)d_in[0];
  const float* emb      = (const float*)d_in[1];
  const float* filt_W   = (const float*)d_in[2];
  const float* filt_b   = (const float*)d_in[3];
  const float* inter_W1 = (const float*)d_in[4];
  const float* inter_b1 = (const float*)d_in[5];
  const float* inter_W2 = (const float*)d_in[6];
  const float* inter_b2 = (const float*)d_in[7];
  const float* mix_W1   = (const float*)d_in[8];
  const float* mix_b1   = (const float*)d_in[9];
  const float* mix_W2   = (const float*)d_in[10];
  const float* mix_b2   = (const float*)d_in[11];
  const float* mix_Wmu  = (const float*)d_in[12];
  const int*   x        = (const int*)d_in[13];
  const int*   idx_i    = (const int*)d_in[14];
  const int*   idx_j    = (const int*)d_in[15];
  const int*   batch    = (const int*)d_in[16];
  float* out = (float*)d_out;

  if (ws_size < WS_NEEDED_BYTES) return;  // pure-poison output => ws too small

  float* wsf    = (float*)d_ws;
  float* t      = wsf + OFF_T;     // t and t2; first E ints = edge_ord during setup
  float* rec    = wsf + OFF_REC;
  float* q      = wsf + OFF_Q;
  float* h      = wsf + OFF_H;     // also g
  float* mu0    = wsf + OFF_MU0;
  float* mu1    = wsf + OFF_MU1;
  float* ctx    = wsf + OFF_CTX;
  float* mm     = wsf + OFF_MM;
  int* wsi      = (int*)(wsf + OFF_INT);
  int* counts   = wsi;
  int* cursor   = wsi + N_ATOMS;
  int* row_ptr  = wsi + 2 * N_ATOMS;
  int* edge_ord = (int*)t;         // aliased; dead after prep_kernel

  // CSR + edge records
  hipMemsetAsync(counts, 0, 2 * N_ATOMS * sizeof(int), stream);  // counts + cursor
  hist_kernel<<<N_EDGES/256, 256, 0, stream>>>(idx_i, counts);
  scan_kernel<<<1, 256, 0, stream>>>(counts, row_ptr);
  scatter_kernel<<<N_EDGES/256, 256, 0, stream>>>(idx_i, row_ptr, cursor, edge_ord);
  prep_kernel<<<N_EDGES/256, 256, 0, stream>>>(pos, idx_i, idx_j, edge_ord, rec);
  init_kernel<<<N_ATOMS*128/256, 256, 0, stream>>>(x, emb, q);

  float* mu_c = mu0;
  float* mu_n = mu1;
  for (int l = 0; l < 3; ++l) {
    // h = silu(q @ W1^T + b1) @ W2^T + b2
    gemm_mfma<1><<<dim3(128, 2), 256, 0, stream>>>(
        q, inter_W1 + (size_t)l*128*128, inter_b1 + (size_t)l*128, t, 16384, 128, 128);
    gemm_mfma<0><<<dim3(128, 6), 256, 0, stream>>>(
        t, inter_W2 + (size_t)l*384*128, inter_b2 + (size_t)l*384, h, 16384, 384, 128);
    // message passing (updates q in place, writes mu_n = mu_c + dmu)
    if (l == 0)
      edge_kernel<1><<<N_ATOMS/2, 256, 0, stream>>>(
          rec, filt_W, filt_b, h, mu_c, row_ptr, q, mu_n);
    else
      edge_kernel<0><<<N_ATOMS/2, 256, 0, stream>>>(
          rec, filt_W, filt_b, h, mu_c, row_ptr, q, mu_n);
    // mixing: mm = mu @ Wmu^T  ([3N,128] x [256,128]^T)
    gemm_mfma<0><<<dim3(384, 4), 256, 0, stream>>>(
        mu_n, mix_Wmu + (size_t)l*256*128, nullptr, mm, 49152, 256, 128);
    ctx_kernel<<<N_ATOMS*128/256, 256, 0, stream>>>(q, mm, ctx);
    gemm_mfma<1><<<dim3(128, 2), 256, 0, stream>>>(
        ctx, mix_W1 + (size_t)l*128*256, mix_b1 + (size_t)l*128, t, 16384, 128, 256);
    gemm_mfma<0><<<dim3(128, 6), 256, 0, stream>>>(
        t, mix_W2 + (size_t)l*384*128, mix_b2 + (size_t)l*384, h, 16384, 384, 128);
    mixup_kernel<<<N_ATOMS*128/256, 256, 0, stream>>>(h, mm, q, mu_n);
    float* tmp = mu_c; mu_c = mu_n; mu_n = tmp;
  }
  readout_kernel<<<512, 128, 0, stream>>>(q, batch, out);
}